// Round 10
// baseline (85.533 us; speedup 1.0000x reference)
//
#include <hip/hip_runtime.h>

#define HW  (1024u*1024u)
#define CHW (2u*HW)
#define MAXP 65536u
#define LABEL_OFF 1048576u
#define SCORE_OFF 1572864u
#define NINF (-3.0e38f)

__device__ __forceinline__ float max3f(float a, float b, float c) {
    return fmaxf(fmaxf(a, b), c);
}

// ---- K1: fused 7x7 NMS mask + lookback prefix + ordered scatter ----
// 1024 blocks; bid = 8*cib + b  (batch b = bid&7, chunk-in-batch cib = bid>>3).
// Chunk id monotone in dispatch id within each batch -> predecessor-only spin
// is deadlock-free under in-order workgroup dispatch. chunkCount zeroed by
// hipMemsetAsync before launch; stored value = count+1 (0 == not ready).
__global__ __launch_bounds__(256, 4) void fused_nms(const float* __restrict__ map,
                                                    unsigned* chunkCount,
                                                    float* __restrict__ out) {
    __shared__ float4 rowbuf[2][2][258];        // [parity][rowInPair][col4+pads]
    __shared__ __align__(8) unsigned lbits[512]; // this chunk's 512 u32 mask words
    __shared__ unsigned sred[4];
    __shared__ unsigned swred[4];
    __shared__ int wsum[4];

    int bid0 = blockIdx.x;
    int b = bid0 & 7;                           // batch
    int cib = bid0 >> 3;                        // chunk in batch, 0..127
    int img = b * 2 + (cib >> 6);               // b*2 + channel
    int stripe = cib & 63;
    int r0 = stripe << 4;
    int tid = threadIdx.x;
    int lane = tid & 63, wv = tid >> 6;
    const float4* __restrict__ base = (const float4*)(map + ((size_t)img << 20));
    const float4 ninf4 = make_float4(NINF, NINF, NINF, NINF);

    if (tid < 8) {                              // NINF pads at [*][*][0] and [*][*][257]
        rowbuf[(tid >> 2) & 1][(tid >> 1) & 1][(tid & 1) * 257] = ninf4;
    }

    // column-validity nibble (cols 6..1017 valid)
    int c0 = tid * 4;
    int cvm = 0;
    #pragma unroll
    for (int j = 0; j < 4; ++j) {
        int cc = c0 + j;
        if (cc >= 6 && cc <= 1017) cvm |= (1 << j);
    }

    // rolling 12-slot window: input row q -> slot (q - r0 + 3) mod 12
    float4 w[12];
    #pragma unroll
    for (int k = 0; k < 10; ++k) {              // rows r0-3 .. r0+6
        int rr = r0 - 3 + k;
        w[k] = ((unsigned)rr < 1024u) ? base[rr * 256 + tid] : ninf4;
    }

    unsigned cnt = 0;

    #pragma unroll
    for (int p = 0; p < 8; ++p) {               // pair rows rA = r0+2p, rB = rA+1
        int rA = r0 + 2 * p;
        if (p < 6) {                            // prefetch rows rA+7, rA+8 (iter p+2)
            int q1 = rA + 7, q2 = rA + 8;
            w[(2 * p + 10) % 12] = ((unsigned)q1 < 1024u) ? base[q1 * 256 + tid] : ninf4;
            w[(2 * p + 11) % 12] = ((unsigned)q2 < 1024u) ? base[q2 * 256 + tid] : ninf4;
        }
        float4 s0 = w[(2 * p + 0) % 12], s1 = w[(2 * p + 1) % 12];
        float4 s2 = w[(2 * p + 2) % 12], s3 = w[(2 * p + 3) % 12];
        float4 s4 = w[(2 * p + 4) % 12], s5 = w[(2 * p + 5) % 12];
        float4 s6 = w[(2 * p + 6) % 12], s7 = w[(2 * p + 7) % 12];

        // vertical: common6 = max(rows rA-2..rA+3); vmA = max(c6,rA-3); vmB = max(c6,rA+4)
        float4 c6, vmA, vmB;
        c6.x = fmaxf(max3f(s1.x, s2.x, s3.x), max3f(s4.x, s5.x, s6.x));
        c6.y = fmaxf(max3f(s1.y, s2.y, s3.y), max3f(s4.y, s5.y, s6.y));
        c6.z = fmaxf(max3f(s1.z, s2.z, s3.z), max3f(s4.z, s5.z, s6.z));
        c6.w = fmaxf(max3f(s1.w, s2.w, s3.w), max3f(s4.w, s5.w, s6.w));
        vmA.x = fmaxf(c6.x, s0.x); vmB.x = fmaxf(c6.x, s7.x);
        vmA.y = fmaxf(c6.y, s0.y); vmB.y = fmaxf(c6.y, s7.y);
        vmA.z = fmaxf(c6.z, s0.z); vmB.z = fmaxf(c6.z, s7.z);
        vmA.w = fmaxf(c6.w, s0.w); vmB.w = fmaxf(c6.w, s7.w);

        rowbuf[p & 1][0][tid + 1] = vmA;
        rowbuf[p & 1][1][tid + 1] = vmB;
        __syncthreads();
        float4 LA = rowbuf[p & 1][0][tid], RA = rowbuf[p & 1][0][tid + 2];
        float4 LB = rowbuf[p & 1][1][tid], RB = rowbuf[p & 1][1][tid + 2];

        // horizontal 7-max
        float mA0 = max3f(max3f(LA.y, LA.z, LA.w),  max3f(vmA.x, vmA.y, vmA.z), vmA.w);
        float mA1 = max3f(max3f(LA.z, LA.w, vmA.x), max3f(vmA.y, vmA.z, vmA.w), RA.x);
        float mA2 = max3f(max3f(LA.w, vmA.x, vmA.y), max3f(vmA.z, vmA.w, RA.x), RA.y);
        float mA3 = max3f(max3f(vmA.x, vmA.y, vmA.z), max3f(vmA.w, RA.x, RA.y), RA.z);
        float mB0 = max3f(max3f(LB.y, LB.z, LB.w),  max3f(vmB.x, vmB.y, vmB.z), vmB.w);
        float mB1 = max3f(max3f(LB.z, LB.w, vmB.x), max3f(vmB.y, vmB.z, vmB.w), RB.x);
        float mB2 = max3f(max3f(LB.w, vmB.x, vmB.y), max3f(vmB.z, vmB.w, RB.x), RB.y);
        float mB3 = max3f(max3f(vmB.x, vmB.y, vmB.z), max3f(vmB.w, RB.x, RB.y), RB.z);

        float4 ctrA = s3, ctrB = s4;             // original rows rA, rB
        int fA0 = (ctrA.x == mA0) & (ctrA.x > 0.5f);
        int fA1 = (ctrA.y == mA1) & (ctrA.y > 0.5f);
        int fA2 = (ctrA.z == mA2) & (ctrA.z > 0.5f);
        int fA3 = (ctrA.w == mA3) & (ctrA.w > 0.5f);
        int fB0 = (ctrB.x == mB0) & (ctrB.x > 0.5f);
        int fB1 = (ctrB.y == mB1) & (ctrB.y > 0.5f);
        int fB2 = (ctrB.z == mB2) & (ctrB.z > 0.5f);
        int fB3 = (ctrB.w == mB3) & (ctrB.w > 0.5f);
        int nibA = (fA0 | (fA1 << 1) | (fA2 << 2) | (fA3 << 3)) & cvm;
        int nibB = (fB0 | (fB1 << 1) | (fB2 << 2) | (fB3 << 3)) & cvm;
        int rowokA = (rA >= 6) & (rA <= 1017);
        int rowokB = ((rA + 1) >= 6) & ((rA + 1) <= 1017);
        nibA = rowokA ? nibA : 0;
        nibB = rowokB ? nibB : 0;

        cnt += (unsigned)(__popc((unsigned)nibA) + __popc((unsigned)nibB));

        // assemble u32 half-words: 8-lane group g -> cols 32g..32g+31 of the row
        unsigned vA = (unsigned)nibA << ((lane & 7) * 4);
        unsigned vB = (unsigned)nibB << ((lane & 7) * 4);
        vA |= __shfl_xor(vA, 1, 64); vB |= __shfl_xor(vB, 1, 64);
        vA |= __shfl_xor(vA, 2, 64); vB |= __shfl_xor(vB, 2, 64);
        vA |= __shfl_xor(vA, 4, 64); vB |= __shfl_xor(vB, 4, 64);
        if ((lane & 7) == 0) {
            int widx = (2 * p) * 32 + wv * 8 + (lane >> 3);  // u32 idx within chunk
            lbits[widx]      = vA;
            lbits[widx + 32] = vB;               // row rA+1
        }
    }

    // publish per-chunk count (count+1; 0 = not ready)
    for (int off = 32; off; off >>= 1) cnt += __shfl_down(cnt, off, 64);
    if (lane == 0) sred[wv] = cnt;
    __syncthreads();
    if (tid == 0) {
        unsigned tot = sred[0] + sred[1] + sred[2] + sred[3];
        __hip_atomic_store(&chunkCount[(b << 7) + cib], tot + 1u,
                           __ATOMIC_RELEASE, __HIP_MEMORY_SCOPE_AGENT);
    }

    // ---- lookback: sum predecessor counts (deadlock-free: preds have smaller bid) ----
    unsigned myv = 0;
    if (tid < cib) {
        unsigned v;
        do {
            v = __hip_atomic_load(&chunkCount[(b << 7) + tid],
                                  __ATOMIC_ACQUIRE, __HIP_MEMORY_SCOPE_AGENT);
        } while (v == 0u);
        myv = v - 1u;
    }
    for (int off = 32; off; off >>= 1) myv += __shfl_down(myv, off, 64);
    if (lane == 0) swred[wv] = myv;
    __syncthreads();
    unsigned sbase = swred[0] + swred[1] + swred[2] + swred[3];

    // ---- scatter own chunk from LDS words ----
    unsigned long long wd = ((const unsigned long long*)lbits)[tid];
    int cnt2 = __popcll(wd);
    int incl = cnt2;
    #pragma unroll
    for (int off = 1; off < 64; off <<= 1) {
        int n = __shfl_up(incl, off, 64);
        if (lane >= off) incl += n;
    }
    if (lane == 63) wsum[wv] = incl;
    __syncthreads();

    int wpre = 0;
    #pragma unroll
    for (int k = 0; k < 4; ++k) if (k < wv) wpre += wsum[k];
    unsigned obase = sbase + (unsigned)wpre + (unsigned)(incl - cnt2);
    unsigned wib = ((unsigned)cib) * 256u + (unsigned)tid;   // u64 word idx in batch

    unsigned long long m = wd;
    unsigned n = 0;
    while (m) {
        int bit = __builtin_ctzll(m);
        m &= m - 1;
        unsigned slot = obase + n;
        n++;
        if (slot < MAXP) {
            unsigned flat = wib * 64u + (unsigned)bit;       // < 2^21
            unsigned c = flat >> 20;
            unsigned h = (flat >> 10) & 1023u;
            unsigned wcol = flat & 1023u;
            float score = map[(size_t)b * CHW + flat];
            unsigned o = b * MAXP + slot;
            out[2u * o]         = (float)wcol;               // x
            out[2u * o + 1]     = (float)h;                  // y
            out[LABEL_OFF + o]  = (float)(c + 1u);           // label
            out[SCORE_OFF + o]  = score;                     // score
        }
    }
}

// ---- K2: tail padding. Runs after K1 completes (kernel boundary = full flush).
// block = b*128 + cib; pads its 512-slot slice where slot >= batch total.
__global__ __launch_bounds__(256) void tail_pad(const unsigned* __restrict__ chunkCount,
                                                float* __restrict__ out) {
    int bid = blockIdx.x;
    int b = bid >> 7, cib = bid & 127;
    int tid = threadIdx.x;
    int lane = tid & 63, wv = tid >> 6;
    __shared__ unsigned swred[4];

    unsigned v = (tid < 128) ? (chunkCount[(b << 7) + tid] - 1u) : 0u;
    for (int off = 32; off; off >>= 1) v += __shfl_down(v, off, 64);
    if (lane == 0) swred[wv] = v;
    __syncthreads();
    unsigned total = swred[0] + swred[1] + swred[2] + swred[3];

    #pragma unroll
    for (int k = 0; k < 2; ++k) {
        unsigned slot = ((unsigned)cib) * 512u + (unsigned)tid + (unsigned)k * 256u;
        if (slot >= total) {                     // slot < 65536 by construction
            unsigned o = b * MAXP + slot;
            float2 neg1; neg1.x = -1.0f; neg1.y = -1.0f;
            ((float2*)out)[o]   = neg1;          // coords (x,y) = -1
            out[LABEL_OFF + o]  = 0.0f;
            out[SCORE_OFF + o]  = 0.0f;
        }
    }
}

extern "C" void kernel_launch(void* const* d_in, const int* in_sizes, int n_in,
                              void* d_out, int out_size, void* d_ws, size_t ws_size,
                              hipStream_t stream) {
    const float* map = (const float*)d_in[0];
    float* out = (float*)d_out;
    unsigned* chunkCount = (unsigned*)d_ws;      // 1024 u32

    hipMemsetAsync(d_ws, 0, 4096, stream);       // clear ready flags (graph-safe)
    fused_nms<<<1024, 256, 0, stream>>>(map, chunkCount, out);
    tail_pad<<<1024, 256, 0, stream>>>(chunkCount, out);
}

// Round 11
// 49.906 us; speedup vs baseline: 1.7139x; 1.7139x over previous
//
#include <hip/hip_runtime.h>

#define HW  (1024u*1024u)
#define CHW (2u*HW)
#define MAXP 65536u
#define LABEL_OFF 1048576u
#define SCORE_OFF 1572864u
#define NINF (-3.0e38f)

__device__ __forceinline__ float max3f(float a, float b, float c) {
    return fmaxf(fmaxf(a, b), c);
}

// ---- A: 7x7 NMS mask + per-chunk count ----
// 1024 blocks, XCD-swizzled; block = one 16-row stripe of one image = one chunk
// rolling 12-slot register window, prefetch depth = 2 pair-iterations
// NOTE round 11: launched TWICE (idempotent) to measure mask_dur via total-time delta.
__global__ __launch_bounds__(256, 4) void mask_kernel(const float* __restrict__ map,
                                                      unsigned* __restrict__ bits32,
                                                      unsigned* __restrict__ chunkCount) {
    __shared__ float4 rowbuf[2][2][258];       // [parity][rowInPair][col4+pads]
    __shared__ unsigned sred[4];
    int bid0 = blockIdx.x;
    int bid = (bid0 & 7) * 128 + (bid0 >> 3);  // XCD swizzle (bijective: 1024 % 8 == 0)
    int tid = threadIdx.x;
    int stripe = bid & 63;
    int img = bid >> 6;                        // b*2 + c
    int r0 = stripe << 4;
    int lane = tid & 63, wv = tid >> 6;
    const float4* __restrict__ base = (const float4*)(map + ((size_t)img << 20));

    if (tid < 8) {                             // NINF pads at [*][*][0] and [*][*][257]
        float4 n4 = make_float4(NINF, NINF, NINF, NINF);
        rowbuf[(tid >> 2) & 1][(tid >> 1) & 1][(tid & 1) * 257] = n4;
    }

    // column-validity nibble (cols 6..1017 valid)
    int c0 = tid * 4;
    int cvm = 0;
    #pragma unroll
    for (int j = 0; j < 4; ++j) {
        int cc = c0 + j;
        if (cc >= 6 && cc <= 1017) cvm |= (1 << j);
    }

    // rolling 12-slot window: input row q -> slot (q - r0 + 3) mod 12
    float4 w[12];
    #pragma unroll
    for (int k = 0; k < 10; ++k) {             // rows r0-3 .. r0+6
        int rr = r0 - 3 + k;
        w[k] = ((unsigned)rr < 1024u) ? base[rr * 256 + tid]
                                      : make_float4(NINF, NINF, NINF, NINF);
    }

    unsigned cnt = 0;

    #pragma unroll
    for (int p = 0; p < 8; ++p) {              // pair rows rA = r0+2p, rB = rA+1
        int rA = r0 + 2 * p;
        if (p < 6) {                           // prefetch rows rA+7, rA+8 (for iter p+2)
            int q1 = rA + 7, q2 = rA + 8;
            w[(2 * p + 10) % 12] = ((unsigned)q1 < 1024u) ? base[q1 * 256 + tid]
                                                          : make_float4(NINF, NINF, NINF, NINF);
            w[(2 * p + 11) % 12] = ((unsigned)q2 < 1024u) ? base[q2 * 256 + tid]
                                                          : make_float4(NINF, NINF, NINF, NINF);
        }
        float4 s0 = w[(2 * p + 0) % 12], s1 = w[(2 * p + 1) % 12];
        float4 s2 = w[(2 * p + 2) % 12], s3 = w[(2 * p + 3) % 12];
        float4 s4 = w[(2 * p + 4) % 12], s5 = w[(2 * p + 5) % 12];
        float4 s6 = w[(2 * p + 6) % 12], s7 = w[(2 * p + 7) % 12];

        // vertical: common6 = max(rows rA-2..rA+3); vmA = max(c6, rA-3); vmB = max(c6, rA+4)
        float4 c6, vmA, vmB;
        c6.x = fmaxf(max3f(s1.x, s2.x, s3.x), max3f(s4.x, s5.x, s6.x));
        c6.y = fmaxf(max3f(s1.y, s2.y, s3.y), max3f(s4.y, s5.y, s6.y));
        c6.z = fmaxf(max3f(s1.z, s2.z, s3.z), max3f(s4.z, s5.z, s6.z));
        c6.w = fmaxf(max3f(s1.w, s2.w, s3.w), max3f(s4.w, s5.w, s6.w));
        vmA.x = fmaxf(c6.x, s0.x); vmB.x = fmaxf(c6.x, s7.x);
        vmA.y = fmaxf(c6.y, s0.y); vmB.y = fmaxf(c6.y, s7.y);
        vmA.z = fmaxf(c6.z, s0.z); vmB.z = fmaxf(c6.z, s7.z);
        vmA.w = fmaxf(c6.w, s0.w); vmB.w = fmaxf(c6.w, s7.w);

        rowbuf[p & 1][0][tid + 1] = vmA;
        rowbuf[p & 1][1][tid + 1] = vmB;
        __syncthreads();
        float4 LA = rowbuf[p & 1][0][tid], RA = rowbuf[p & 1][0][tid + 2];
        float4 LB = rowbuf[p & 1][1][tid], RB = rowbuf[p & 1][1][tid + 2];

        // horizontal 7-max
        float mA0 = max3f(max3f(LA.y, LA.z, LA.w),  max3f(vmA.x, vmA.y, vmA.z), vmA.w);
        float mA1 = max3f(max3f(LA.z, LA.w, vmA.x), max3f(vmA.y, vmA.z, vmA.w), RA.x);
        float mA2 = max3f(max3f(LA.w, vmA.x, vmA.y), max3f(vmA.z, vmA.w, RA.x), RA.y);
        float mA3 = max3f(max3f(vmA.x, vmA.y, vmA.z), max3f(vmA.w, RA.x, RA.y), RA.z);
        float mB0 = max3f(max3f(LB.y, LB.z, LB.w),  max3f(vmB.x, vmB.y, vmB.z), vmB.w);
        float mB1 = max3f(max3f(LB.z, LB.w, vmB.x), max3f(vmB.y, vmB.z, vmB.w), RB.x);
        float mB2 = max3f(max3f(LB.w, vmB.x, vmB.y), max3f(vmB.z, vmB.w, RB.x), RB.y);
        float mB3 = max3f(max3f(vmB.x, vmB.y, vmB.z), max3f(vmB.w, RB.x, RB.y), RB.z);

        float4 ctrA = s3, ctrB = s4;            // original rows rA, rB
        int fA0 = (ctrA.x == mA0) & (ctrA.x > 0.5f);
        int fA1 = (ctrA.y == mA1) & (ctrA.y > 0.5f);
        int fA2 = (ctrA.z == mA2) & (ctrA.z > 0.5f);
        int fA3 = (ctrA.w == mA3) & (ctrA.w > 0.5f);
        int fB0 = (ctrB.x == mB0) & (ctrB.x > 0.5f);
        int fB1 = (ctrB.y == mB1) & (ctrB.y > 0.5f);
        int fB2 = (ctrB.z == mB2) & (ctrB.z > 0.5f);
        int fB3 = (ctrB.w == mB3) & (ctrB.w > 0.5f);
        int nibA = (fA0 | (fA1 << 1) | (fA2 << 2) | (fA3 << 3)) & cvm;
        int nibB = (fB0 | (fB1 << 1) | (fB2 << 2) | (fB3 << 3)) & cvm;
        int rowokA = (rA >= 6) & (rA <= 1017);
        int rowokB = ((rA + 1) >= 6) & ((rA + 1) <= 1017);
        nibA = rowokA ? nibA : 0;
        nibB = rowokB ? nibB : 0;

        cnt += (unsigned)(__popc((unsigned)nibA) + __popc((unsigned)nibB));

        // assemble u32 half-words: 8-lane group g = lanes 8g..8g+7 -> cols 32g..32g+31
        unsigned vA = (unsigned)nibA << ((lane & 7) * 4);
        unsigned vB = (unsigned)nibB << ((lane & 7) * 4);
        vA |= __shfl_xor(vA, 1, 64); vB |= __shfl_xor(vB, 1, 64);
        vA |= __shfl_xor(vA, 2, 64); vB |= __shfl_xor(vB, 2, 64);
        vA |= __shfl_xor(vA, 4, 64); vB |= __shfl_xor(vB, 4, 64);
        if ((lane & 7) == 0) {
            // u32 index = img*32768 + row*32 + wv*8 + (lane>>3)
            size_t wbase = ((size_t)img << 15) + ((size_t)rA << 5) + wv * 8 + (lane >> 3);
            bits32[wbase]      = vA;
            bits32[wbase + 32] = vB;            // row rA+1
        }
    }

    // per-chunk count (block == one chunk)
    for (int off = 32; off; off >>= 1) cnt += __shfl_down(cnt, off, 64);
    if (lane == 0) sred[wv] = cnt;
    __syncthreads();
    if (tid == 0) chunkCount[(img << 6) + stripe] = sred[0] + sred[1] + sred[2] + sred[3];
}

// ---- B: fused scan + ordered scatter + tail padding (float32 outputs) ----
// block = b*128 + chunk_in_batch; 256 threads, one u64 word each
__global__ __launch_bounds__(256) void scan_scatter(const float* __restrict__ map,
                                                    const unsigned long long* __restrict__ bits,
                                                    const unsigned* __restrict__ chunkCount,
                                                    float* __restrict__ out) {
    int blk = blockIdx.x;
    int b = blk >> 7, cib = blk & 127;
    int tid = threadIdx.x;
    int lane = tid & 63, wv = tid >> 6;

    __shared__ unsigned long long sw[4];
    __shared__ unsigned sbase, stotal;
    __shared__ int wsum[4];

    // packed reduce: low32 = sum over chunks < cib (base), high32 = sum over all (total)
    unsigned cc = (tid < 128) ? chunkCount[b * 128 + tid] : 0u;
    unsigned long long v = ((tid < cib) ? (unsigned long long)cc : 0ull)
                         | ((unsigned long long)cc << 32);
    for (int off = 32; off; off >>= 1) v += __shfl_down(v, off, 64);
    if (lane == 0) sw[wv] = v;
    __syncthreads();
    if (tid == 0) {
        unsigned long long t = sw[0] + sw[1] + sw[2] + sw[3];
        sbase  = (unsigned)t;
        stotal = (unsigned)(t >> 32);
    }

    // own word + intra-block exclusive prefix of popcounts (shfl scan)
    unsigned long long wd = bits[(size_t)blk * 256 + tid];
    int cnt = __popcll(wd);
    int incl = cnt;
    #pragma unroll
    for (int off = 1; off < 64; off <<= 1) {
        int n = __shfl_up(incl, off, 64);
        if (lane >= off) incl += n;
    }
    if (lane == 63) wsum[wv] = incl;
    __syncthreads();                            // also publishes sbase/stotal

    int wpre = 0;
    #pragma unroll
    for (int k = 0; k < 4; ++k) if (k < wv) wpre += wsum[k];
    unsigned base = sbase + (unsigned)wpre + (unsigned)(incl - cnt);
    unsigned wib = ((unsigned)cib) * 256u + (unsigned)tid;       // word idx in batch

    unsigned long long m = wd;
    unsigned n = 0;
    while (m) {
        int bit = __builtin_ctzll(m);
        m &= m - 1;
        unsigned slot = base + n;
        n++;
        if (slot < MAXP) {
            unsigned flat = wib * 64u + (unsigned)bit;   // < 2^21
            unsigned c = flat >> 20;
            unsigned h = (flat >> 10) & 1023u;
            unsigned wcol = flat & 1023u;
            float score = map[(size_t)b * CHW + flat];
            unsigned o = b * MAXP + slot;
            out[2u * o]         = (float)wcol;           // x
            out[2u * o + 1]     = (float)h;              // y
            out[LABEL_OFF + o]  = (float)(c + 1u);       // label
            out[SCORE_OFF + o]  = score;                 // score
        }
    }

    // tail padding: this block owns slots [cib*512, cib*512+512)
    unsigned total = stotal;
    #pragma unroll
    for (int k = 0; k < 2; ++k) {
        unsigned slot = ((unsigned)cib) * 512u + (unsigned)tid + (unsigned)k * 256u;
        if (slot >= total) {                    // slot < 65536 by construction
            unsigned o = b * MAXP + slot;
            float2 neg1; neg1.x = -1.0f; neg1.y = -1.0f;
            ((float2*)out)[o]   = neg1;          // coords (x,y) = -1
            out[LABEL_OFF + o]  = 0.0f;
            out[SCORE_OFF + o]  = 0.0f;
        }
    }
}

extern "C" void kernel_launch(void* const* d_in, const int* in_sizes, int n_in,
                              void* d_out, int out_size, void* d_ws, size_t ws_size,
                              hipStream_t stream) {
    const float* map = (const float*)d_in[0];
    float* out = (float*)d_out;
    unsigned long long* bits = (unsigned long long*)d_ws;        // 262144 u64 = 2 MB
    unsigned* chunkCount = (unsigned*)((char*)d_ws + 2097152);   // 1024 u32

    // MEASUREMENT ROUND: mask launched twice (idempotent, deterministic).
    // dur_us - 33.1 ~= mask_kernel duration; remainder = scan_scatter + overhead.
    mask_kernel<<<1024, 256, 0, stream>>>(map, (unsigned*)d_ws, chunkCount);
    mask_kernel<<<1024, 256, 0, stream>>>(map, (unsigned*)d_ws, chunkCount);
    scan_scatter<<<1024, 256, 0, stream>>>(map, bits, chunkCount, out);
}

// Round 12
// 31.024 us; speedup vs baseline: 2.7570x; 1.6086x over previous
//
#include <hip/hip_runtime.h>

#define HW  (1024u*1024u)
#define CHW (2u*HW)
#define MAXP 65536u
#define LABEL_OFF 1048576u
#define SCORE_OFF 1572864u
#define NINF (-3.0e38f)

__device__ __forceinline__ float max3f(float a, float b, float c) {
    return fmaxf(fmaxf(a, b), c);
}

// ---- A: 7x7 NMS mask + per-chunk count (unchanged R7 body) ----
__global__ __launch_bounds__(256, 4) void mask_kernel(const float* __restrict__ map,
                                                      unsigned* __restrict__ bits32,
                                                      unsigned* __restrict__ chunkCount) {
    __shared__ float4 rowbuf[2][2][258];       // [parity][rowInPair][col4+pads]
    __shared__ unsigned sred[4];
    int bid0 = blockIdx.x;
    int bid = (bid0 & 7) * 128 + (bid0 >> 3);  // XCD swizzle (bijective: 1024 % 8 == 0)
    int tid = threadIdx.x;
    int stripe = bid & 63;
    int img = bid >> 6;                        // b*2 + c
    int r0 = stripe << 4;
    int lane = tid & 63, wv = tid >> 6;
    const float4* __restrict__ base = (const float4*)(map + ((size_t)img << 20));

    if (tid < 8) {                             // NINF pads at [*][*][0] and [*][*][257]
        float4 n4 = make_float4(NINF, NINF, NINF, NINF);
        rowbuf[(tid >> 2) & 1][(tid >> 1) & 1][(tid & 1) * 257] = n4;
    }

    // column-validity nibble (cols 6..1017 valid)
    int c0 = tid * 4;
    int cvm = 0;
    #pragma unroll
    for (int j = 0; j < 4; ++j) {
        int cc = c0 + j;
        if (cc >= 6 && cc <= 1017) cvm |= (1 << j);
    }

    // rolling 12-slot window: input row q -> slot (q - r0 + 3) mod 12
    float4 w[12];
    #pragma unroll
    for (int k = 0; k < 10; ++k) {             // rows r0-3 .. r0+6
        int rr = r0 - 3 + k;
        w[k] = ((unsigned)rr < 1024u) ? base[rr * 256 + tid]
                                      : make_float4(NINF, NINF, NINF, NINF);
    }

    unsigned cnt = 0;

    #pragma unroll
    for (int p = 0; p < 8; ++p) {              // pair rows rA = r0+2p, rB = rA+1
        int rA = r0 + 2 * p;
        if (p < 6) {                           // prefetch rows rA+7, rA+8 (for iter p+2)
            int q1 = rA + 7, q2 = rA + 8;
            w[(2 * p + 10) % 12] = ((unsigned)q1 < 1024u) ? base[q1 * 256 + tid]
                                                          : make_float4(NINF, NINF, NINF, NINF);
            w[(2 * p + 11) % 12] = ((unsigned)q2 < 1024u) ? base[q2 * 256 + tid]
                                                          : make_float4(NINF, NINF, NINF, NINF);
        }
        float4 s0 = w[(2 * p + 0) % 12], s1 = w[(2 * p + 1) % 12];
        float4 s2 = w[(2 * p + 2) % 12], s3 = w[(2 * p + 3) % 12];
        float4 s4 = w[(2 * p + 4) % 12], s5 = w[(2 * p + 5) % 12];
        float4 s6 = w[(2 * p + 6) % 12], s7 = w[(2 * p + 7) % 12];

        // vertical: common6 = max(rows rA-2..rA+3); vmA = max(c6, rA-3); vmB = max(c6, rA+4)
        float4 c6, vmA, vmB;
        c6.x = fmaxf(max3f(s1.x, s2.x, s3.x), max3f(s4.x, s5.x, s6.x));
        c6.y = fmaxf(max3f(s1.y, s2.y, s3.y), max3f(s4.y, s5.y, s6.y));
        c6.z = fmaxf(max3f(s1.z, s2.z, s3.z), max3f(s4.z, s5.z, s6.z));
        c6.w = fmaxf(max3f(s1.w, s2.w, s3.w), max3f(s4.w, s5.w, s6.w));
        vmA.x = fmaxf(c6.x, s0.x); vmB.x = fmaxf(c6.x, s7.x);
        vmA.y = fmaxf(c6.y, s0.y); vmB.y = fmaxf(c6.y, s7.y);
        vmA.z = fmaxf(c6.z, s0.z); vmB.z = fmaxf(c6.z, s7.z);
        vmA.w = fmaxf(c6.w, s0.w); vmB.w = fmaxf(c6.w, s7.w);

        rowbuf[p & 1][0][tid + 1] = vmA;
        rowbuf[p & 1][1][tid + 1] = vmB;
        __syncthreads();
        float4 LA = rowbuf[p & 1][0][tid], RA = rowbuf[p & 1][0][tid + 2];
        float4 LB = rowbuf[p & 1][1][tid], RB = rowbuf[p & 1][1][tid + 2];

        // horizontal 7-max
        float mA0 = max3f(max3f(LA.y, LA.z, LA.w),  max3f(vmA.x, vmA.y, vmA.z), vmA.w);
        float mA1 = max3f(max3f(LA.z, LA.w, vmA.x), max3f(vmA.y, vmA.z, vmA.w), RA.x);
        float mA2 = max3f(max3f(LA.w, vmA.x, vmA.y), max3f(vmA.z, vmA.w, RA.x), RA.y);
        float mA3 = max3f(max3f(vmA.x, vmA.y, vmA.z), max3f(vmA.w, RA.x, RA.y), RA.z);
        float mB0 = max3f(max3f(LB.y, LB.z, LB.w),  max3f(vmB.x, vmB.y, vmB.z), vmB.w);
        float mB1 = max3f(max3f(LB.z, LB.w, vmB.x), max3f(vmB.y, vmB.z, vmB.w), RB.x);
        float mB2 = max3f(max3f(LB.w, vmB.x, vmB.y), max3f(vmB.z, vmB.w, RB.x), RB.y);
        float mB3 = max3f(max3f(vmB.x, vmB.y, vmB.z), max3f(vmB.w, RB.x, RB.y), RB.z);

        float4 ctrA = s3, ctrB = s4;            // original rows rA, rB
        int fA0 = (ctrA.x == mA0) & (ctrA.x > 0.5f);
        int fA1 = (ctrA.y == mA1) & (ctrA.y > 0.5f);
        int fA2 = (ctrA.z == mA2) & (ctrA.z > 0.5f);
        int fA3 = (ctrA.w == mA3) & (ctrA.w > 0.5f);
        int fB0 = (ctrB.x == mB0) & (ctrB.x > 0.5f);
        int fB1 = (ctrB.y == mB1) & (ctrB.y > 0.5f);
        int fB2 = (ctrB.z == mB2) & (ctrB.z > 0.5f);
        int fB3 = (ctrB.w == mB3) & (ctrB.w > 0.5f);
        int nibA = (fA0 | (fA1 << 1) | (fA2 << 2) | (fA3 << 3)) & cvm;
        int nibB = (fB0 | (fB1 << 1) | (fB2 << 2) | (fB3 << 3)) & cvm;
        int rowokA = (rA >= 6) & (rA <= 1017);
        int rowokB = ((rA + 1) >= 6) & ((rA + 1) <= 1017);
        nibA = rowokA ? nibA : 0;
        nibB = rowokB ? nibB : 0;

        cnt += (unsigned)(__popc((unsigned)nibA) + __popc((unsigned)nibB));

        // assemble u32 half-words: 8-lane group g = lanes 8g..8g+7 -> cols 32g..32g+31
        unsigned vA = (unsigned)nibA << ((lane & 7) * 4);
        unsigned vB = (unsigned)nibB << ((lane & 7) * 4);
        vA |= __shfl_xor(vA, 1, 64); vB |= __shfl_xor(vB, 1, 64);
        vA |= __shfl_xor(vA, 2, 64); vB |= __shfl_xor(vB, 2, 64);
        vA |= __shfl_xor(vA, 4, 64); vB |= __shfl_xor(vB, 4, 64);
        if ((lane & 7) == 0) {
            // u32 index = img*32768 + row*32 + wv*8 + (lane>>3)
            size_t wbase = ((size_t)img << 15) + ((size_t)rA << 5) + wv * 8 + (lane >> 3);
            bits32[wbase]      = vA;
            bits32[wbase + 32] = vB;            // row rA+1
        }
    }

    // per-chunk count (block == one chunk)
    for (int off = 32; off; off >>= 1) cnt += __shfl_down(cnt, off, 64);
    if (lane == 0) sred[wv] = cnt;
    __syncthreads();
    if (tid == 0) chunkCount[(img << 6) + stripe] = sred[0] + sred[1] + sred[2] + sred[3];
}

// ---- B: scan + ordered scatter + tail pad, 512 threads, one u32 word/thread ----
// blk swizzled to match mask's producer XCD; chunk cib's u32 words = [blk*512, blk*512+512)
__global__ __launch_bounds__(512) void scan_scatter(const float* __restrict__ map,
                                                    const unsigned* __restrict__ bits32,
                                                    const unsigned* __restrict__ chunkCount,
                                                    float* __restrict__ out) {
    int bid0 = blockIdx.x;
    int blk = (bid0 & 7) * 128 + (bid0 >> 3);   // match mask's chunk->XCD mapping
    int b = blk >> 7, cib = blk & 127;
    int tid = threadIdx.x;
    int lane = tid & 63, wv = tid >> 6;         // wv 0..7

    __shared__ unsigned long long sw[8];
    __shared__ unsigned sbase, stotal;
    __shared__ int wsum[8];

    // packed reduce: low32 = sum over chunks < cib (base), high32 = sum over all (total)
    unsigned cc = (tid < 128) ? chunkCount[b * 128 + tid] : 0u;
    unsigned long long v = ((tid < cib) ? (unsigned long long)cc : 0ull)
                         | ((unsigned long long)cc << 32);
    for (int off = 32; off; off >>= 1) v += __shfl_down(v, off, 64);
    if (lane == 0) sw[wv] = v;                  // waves 2..7 contribute 0
    __syncthreads();
    if (tid == 0) {
        unsigned long long t = sw[0] + sw[1] + sw[2] + sw[3] + sw[4] + sw[5] + sw[6] + sw[7];
        sbase  = (unsigned)t;
        stotal = (unsigned)(t >> 32);
    }

    // own u32 word + intra-block exclusive prefix of popcounts
    unsigned wd = bits32[(size_t)blk * 512 + tid];
    int cnt = __popc(wd);
    int incl = cnt;
    #pragma unroll
    for (int off = 1; off < 64; off <<= 1) {
        int n = __shfl_up(incl, off, 64);
        if (lane >= off) incl += n;
    }
    if (lane == 63) wsum[wv] = incl;
    __syncthreads();                            // also publishes sbase/stotal

    int wpre = 0;
    #pragma unroll
    for (int k = 0; k < 8; ++k) if (k < wv) wpre += wsum[k];
    unsigned base = sbase + (unsigned)wpre + (unsigned)(incl - cnt);
    unsigned wib = ((unsigned)cib) * 512u + (unsigned)tid;   // u32 word idx in batch

    unsigned m = wd;
    unsigned n = 0;
    while (m) {
        int bit = __builtin_ctz(m);
        m &= m - 1;
        unsigned slot = base + n;
        n++;
        if (slot < MAXP) {
            unsigned flat = wib * 32u + (unsigned)bit;   // < 2^21
            unsigned c = flat >> 20;
            unsigned h = (flat >> 10) & 1023u;
            unsigned wcol = flat & 1023u;
            float score = map[(size_t)b * CHW + flat];
            unsigned o = b * MAXP + slot;
            out[2u * o]         = (float)wcol;           // x
            out[2u * o + 1]     = (float)h;              // y
            out[LABEL_OFF + o]  = (float)(c + 1u);       // label
            out[SCORE_OFF + o]  = score;                 // score
        }
    }

    // tail padding: exactly one slot per thread in this chunk's 512-slot slice
    unsigned slot = ((unsigned)cib) * 512u + (unsigned)tid;
    if (slot >= stotal) {                        // slot < 65536 by construction
        unsigned o = b * MAXP + slot;
        float2 neg1; neg1.x = -1.0f; neg1.y = -1.0f;
        ((float2*)out)[o]   = neg1;              // coords (x,y) = -1
        out[LABEL_OFF + o]  = 0.0f;
        out[SCORE_OFF + o]  = 0.0f;
    }
}

extern "C" void kernel_launch(void* const* d_in, const int* in_sizes, int n_in,
                              void* d_out, int out_size, void* d_ws, size_t ws_size,
                              hipStream_t stream) {
    const float* map = (const float*)d_in[0];
    float* out = (float*)d_out;
    unsigned* bits32 = (unsigned*)d_ws;                          // 524288 u32 = 2 MB
    unsigned* chunkCount = (unsigned*)((char*)d_ws + 2097152);   // 1024 u32

    mask_kernel<<<1024, 256, 0, stream>>>(map, bits32, chunkCount);
    scan_scatter<<<1024, 512, 0, stream>>>(map, bits32, chunkCount, out);
}

// Round 13
// 29.186 us; speedup vs baseline: 2.9306x; 1.0630x over previous
//
#include <hip/hip_runtime.h>

#define HW  (1024u*1024u)
#define CHW (2u*HW)
#define MAXP 65536u
#define LABEL_OFF 1048576u
#define SCORE_OFF 1572864u
#define NINF (-3.0e38f)
#define PAIRS_PER_CHUNK 512u

__device__ __forceinline__ float max3f(float a, float b, float c) {
    return fmaxf(fmaxf(a, b), c);
}

// ---- A: 7x7 NMS mask + in-order pair emission + per-chunk count ----
// 1024 blocks, XCD-swizzled; block = one 16-row stripe of one image = one chunk.
// Emits compacted (flat_in_batch, score_bits) pairs in ascending-flat order.
__global__ __launch_bounds__(256, 4) void mask_kernel(const float* __restrict__ map,
                                                      uint2* __restrict__ pairs,
                                                      unsigned* __restrict__ chunkCount) {
    __shared__ float4 rowbuf[2][2][258];       // [parity][rowInPair][col4+pads]
    __shared__ unsigned swscan[4];
    int bid0 = blockIdx.x;
    int bid = (bid0 & 7) * 128 + (bid0 >> 3);  // XCD swizzle (bijective: 1024 % 8 == 0)
    int tid = threadIdx.x;
    int stripe = bid & 63;
    int img = bid >> 6;                        // b*2 + c
    int r0 = stripe << 4;
    int lane = tid & 63, wv = tid >> 6;
    const float4* __restrict__ base = (const float4*)(map + ((size_t)img << 20));
    const size_t pbase = (size_t)bid * PAIRS_PER_CHUNK;

    if (tid < 8) {                             // NINF pads at [*][*][0] and [*][*][257]
        float4 n4 = make_float4(NINF, NINF, NINF, NINF);
        rowbuf[(tid >> 2) & 1][(tid >> 1) & 1][(tid & 1) * 257] = n4;
    }

    // column-validity nibble (cols 6..1017 valid)
    int c0 = tid * 4;
    int cvm = 0;
    #pragma unroll
    for (int j = 0; j < 4; ++j) {
        int cc = c0 + j;
        if (cc >= 6 && cc <= 1017) cvm |= (1 << j);
    }

    // rolling 12-slot window: input row q -> slot (q - r0 + 3) mod 12
    float4 w[12];
    #pragma unroll
    for (int k = 0; k < 10; ++k) {             // rows r0-3 .. r0+6
        int rr = r0 - 3 + k;
        w[k] = ((unsigned)rr < 1024u) ? base[rr * 256 + tid]
                                      : make_float4(NINF, NINF, NINF, NINF);
    }

    unsigned chunkOff = 0;                     // peaks emitted so far (uniform)

    #pragma unroll
    for (int p = 0; p < 8; ++p) {              // pair rows rA = r0+2p, rB = rA+1
        int rA = r0 + 2 * p;
        if (p < 6) {                           // prefetch rows rA+7, rA+8 (for iter p+2)
            int q1 = rA + 7, q2 = rA + 8;
            w[(2 * p + 10) % 12] = ((unsigned)q1 < 1024u) ? base[q1 * 256 + tid]
                                                          : make_float4(NINF, NINF, NINF, NINF);
            w[(2 * p + 11) % 12] = ((unsigned)q2 < 1024u) ? base[q2 * 256 + tid]
                                                          : make_float4(NINF, NINF, NINF, NINF);
        }
        float4 s0 = w[(2 * p + 0) % 12], s1 = w[(2 * p + 1) % 12];
        float4 s2 = w[(2 * p + 2) % 12], s3 = w[(2 * p + 3) % 12];
        float4 s4 = w[(2 * p + 4) % 12], s5 = w[(2 * p + 5) % 12];
        float4 s6 = w[(2 * p + 6) % 12], s7 = w[(2 * p + 7) % 12];

        // vertical: common6 = max(rows rA-2..rA+3); vmA = max(c6, rA-3); vmB = max(c6, rA+4)
        float4 c6, vmA, vmB;
        c6.x = fmaxf(max3f(s1.x, s2.x, s3.x), max3f(s4.x, s5.x, s6.x));
        c6.y = fmaxf(max3f(s1.y, s2.y, s3.y), max3f(s4.y, s5.y, s6.y));
        c6.z = fmaxf(max3f(s1.z, s2.z, s3.z), max3f(s4.z, s5.z, s6.z));
        c6.w = fmaxf(max3f(s1.w, s2.w, s3.w), max3f(s4.w, s5.w, s6.w));
        vmA.x = fmaxf(c6.x, s0.x); vmB.x = fmaxf(c6.x, s7.x);
        vmA.y = fmaxf(c6.y, s0.y); vmB.y = fmaxf(c6.y, s7.y);
        vmA.z = fmaxf(c6.z, s0.z); vmB.z = fmaxf(c6.z, s7.z);
        vmA.w = fmaxf(c6.w, s0.w); vmB.w = fmaxf(c6.w, s7.w);

        rowbuf[p & 1][0][tid + 1] = vmA;
        rowbuf[p & 1][1][tid + 1] = vmB;
        __syncthreads();
        float4 LA = rowbuf[p & 1][0][tid], RA = rowbuf[p & 1][0][tid + 2];
        float4 LB = rowbuf[p & 1][1][tid], RB = rowbuf[p & 1][1][tid + 2];

        // horizontal 7-max
        float mA0 = max3f(max3f(LA.y, LA.z, LA.w),  max3f(vmA.x, vmA.y, vmA.z), vmA.w);
        float mA1 = max3f(max3f(LA.z, LA.w, vmA.x), max3f(vmA.y, vmA.z, vmA.w), RA.x);
        float mA2 = max3f(max3f(LA.w, vmA.x, vmA.y), max3f(vmA.z, vmA.w, RA.x), RA.y);
        float mA3 = max3f(max3f(vmA.x, vmA.y, vmA.z), max3f(vmA.w, RA.x, RA.y), RA.z);
        float mB0 = max3f(max3f(LB.y, LB.z, LB.w),  max3f(vmB.x, vmB.y, vmB.z), vmB.w);
        float mB1 = max3f(max3f(LB.z, LB.w, vmB.x), max3f(vmB.y, vmB.z, vmB.w), RB.x);
        float mB2 = max3f(max3f(LB.w, vmB.x, vmB.y), max3f(vmB.z, vmB.w, RB.x), RB.y);
        float mB3 = max3f(max3f(vmB.x, vmB.y, vmB.z), max3f(vmB.w, RB.x, RB.y), RB.z);

        float4 ctrA = s3, ctrB = s4;            // original rows rA, rB
        int fA0 = (ctrA.x == mA0) & (ctrA.x > 0.5f);
        int fA1 = (ctrA.y == mA1) & (ctrA.y > 0.5f);
        int fA2 = (ctrA.z == mA2) & (ctrA.z > 0.5f);
        int fA3 = (ctrA.w == mA3) & (ctrA.w > 0.5f);
        int fB0 = (ctrB.x == mB0) & (ctrB.x > 0.5f);
        int fB1 = (ctrB.y == mB1) & (ctrB.y > 0.5f);
        int fB2 = (ctrB.z == mB2) & (ctrB.z > 0.5f);
        int fB3 = (ctrB.w == mB3) & (ctrB.w > 0.5f);
        int nibA = (fA0 | (fA1 << 1) | (fA2 << 2) | (fA3 << 3)) & cvm;
        int nibB = (fB0 | (fB1 << 1) | (fB2 << 2) | (fB3 << 3)) & cvm;
        int rowokA = (rA >= 6) & (rA <= 1017);
        int rowokB = ((rA + 1) >= 6) & ((rA + 1) <= 1017);
        nibA = rowokA ? nibA : 0;
        nibB = rowokB ? nibB : 0;

        // ---- order-preserving position: packed wave scan + cross-wave sum ----
        unsigned packed = (unsigned)__popc((unsigned)nibA)
                        | ((unsigned)__popc((unsigned)nibB) << 16);
        unsigned incl = packed;
        #pragma unroll
        for (int off = 1; off < 64; off <<= 1) {
            unsigned nn = __shfl_up(incl, off, 64);
            if (lane >= off) incl += nn;
        }
        if (lane == 63) swscan[wv] = incl;
        __syncthreads();
        unsigned excl = incl - packed;
        unsigned preA = 0, preB = 0, sumA = 0, sumB = 0;
        #pragma unroll
        for (int k = 0; k < 4; ++k) {
            unsigned sv = swscan[k];
            if (k < wv) { preA += sv & 0xFFFFu; preB += sv >> 16; }
            sumA += sv & 0xFFFFu; sumB += sv >> 16;
        }
        unsigned posA = chunkOff + preA + (excl & 0xFFFFu);
        unsigned posB = chunkOff + sumA + preB + (excl >> 16);
        chunkOff += sumA + sumB;

        unsigned flatbase = ((unsigned)(img & 1) << 20) | ((unsigned)rA << 10)
                          | ((unsigned)tid * 4u);
        if (nibA & 1) pairs[pbase + posA++] = make_uint2(flatbase + 0u, __float_as_uint(ctrA.x));
        if (nibA & 2) pairs[pbase + posA++] = make_uint2(flatbase + 1u, __float_as_uint(ctrA.y));
        if (nibA & 4) pairs[pbase + posA++] = make_uint2(flatbase + 2u, __float_as_uint(ctrA.z));
        if (nibA & 8) pairs[pbase + posA++] = make_uint2(flatbase + 3u, __float_as_uint(ctrA.w));
        if (nibB & 1) pairs[pbase + posB++] = make_uint2(flatbase + 1024u, __float_as_uint(ctrB.x));
        if (nibB & 2) pairs[pbase + posB++] = make_uint2(flatbase + 1025u, __float_as_uint(ctrB.y));
        if (nibB & 4) pairs[pbase + posB++] = make_uint2(flatbase + 1026u, __float_as_uint(ctrB.z));
        if (nibB & 8) pairs[pbase + posB++] = make_uint2(flatbase + 1027u, __float_as_uint(ctrB.w));
    }

    if (tid == 0) chunkCount[bid] = chunkOff;   // chunk linear id == bid (= b*128+cib)
}

// ---- B: scan + coalesced scatter + tail pad. 512 threads; slot = base + tid ----
__global__ __launch_bounds__(512) void scan_scatter(const uint2* __restrict__ pairs,
                                                    const unsigned* __restrict__ chunkCount,
                                                    float* __restrict__ out) {
    int bid0 = blockIdx.x;
    int blk = (bid0 & 7) * 128 + (bid0 >> 3);   // match mask's chunk->XCD mapping
    int b = blk >> 7, cib = blk & 127;
    int tid = threadIdx.x;
    int lane = tid & 63, wv = tid >> 6;         // wv 0..7

    __shared__ unsigned long long sw[8];
    __shared__ unsigned sbase, stotal;

    // packed reduce: low32 = sum over chunks < cib (base), high32 = sum over all (total)
    unsigned cc = (tid < 128) ? chunkCount[b * 128 + tid] : 0u;
    unsigned long long v = ((tid < cib) ? (unsigned long long)cc : 0ull)
                         | ((unsigned long long)cc << 32);
    for (int off = 32; off; off >>= 1) v += __shfl_down(v, off, 64);
    if (lane == 0) sw[wv] = v;
    __syncthreads();
    if (tid == 0) {
        unsigned long long t = sw[0] + sw[1] + sw[2] + sw[3] + sw[4] + sw[5] + sw[6] + sw[7];
        sbase  = (unsigned)t;
        stotal = (unsigned)(t >> 32);
    }
    __syncthreads();

    unsigned n = chunkCount[blk];
    if (n > PAIRS_PER_CHUNK) n = PAIRS_PER_CHUNK;
    if ((unsigned)tid < n) {
        uint2 pr = pairs[(size_t)blk * PAIRS_PER_CHUNK + tid];
        unsigned slot = sbase + (unsigned)tid;
        if (slot < MAXP) {
            unsigned flat = pr.x;
            unsigned c = flat >> 20;
            unsigned h = (flat >> 10) & 1023u;
            unsigned wcol = flat & 1023u;
            unsigned o = b * MAXP + slot;
            out[2u * o]         = (float)wcol;           // x
            out[2u * o + 1]     = (float)h;              // y
            out[LABEL_OFF + o]  = (float)(c + 1u);       // label
            out[SCORE_OFF + o]  = __uint_as_float(pr.y); // score
        }
    }

    // tail padding: one slot per thread in this chunk's 512-slot slice
    unsigned slot = ((unsigned)cib) * 512u + (unsigned)tid;
    if (slot >= stotal) {                        // slot < 65536 by construction
        unsigned o = b * MAXP + slot;
        float2 neg1; neg1.x = -1.0f; neg1.y = -1.0f;
        ((float2*)out)[o]   = neg1;              // coords (x,y) = -1
        out[LABEL_OFF + o]  = 0.0f;
        out[SCORE_OFF + o]  = 0.0f;
    }
}

extern "C" void kernel_launch(void* const* d_in, const int* in_sizes, int n_in,
                              void* d_out, int out_size, void* d_ws, size_t ws_size,
                              hipStream_t stream) {
    const float* map = (const float*)d_in[0];
    float* out = (float*)d_out;
    uint2* pairs = (uint2*)d_ws;                                 // 1024*512*8B = 4 MB
    unsigned* chunkCount = (unsigned*)((char*)d_ws + 4194304);   // 1024 u32

    mask_kernel<<<1024, 256, 0, stream>>>(map, pairs, chunkCount);
    scan_scatter<<<1024, 512, 0, stream>>>(pairs, chunkCount, out);
}